// Round 5
// baseline (715.593 us; speedup 1.0000x reference)
//
#include <hip/hip_runtime.h>

// Light-field per-pixel 9x9 filter, R5.
// out[b,s,o,h,w] = clip(sum_{i,ky,kx} lf[b,s,i,3h-3+ky,3w-3+kx] * W[s,o,i,h,w,81] + bias, 0, 1)
//
// R4 post-mortem: 194us, ~2.5 TB/s. Remaining overhead: lf loaded 3x (per o)
// as scalar gathers (TA-bound) + per-phase mask muls. R5: i-outer/o-inner,
// 81-tap lf patch held in REGISTERS across the 3 o-phases (masked once),
// 3-way split accumulator; weights keep R4's dbuf global_load_lds staging.
// XCD-chunked block swizzle for lf L2 locality.

#define ST 9
#define INC 3
#define OUTC 3
#define OHH 128
#define OWW 128
#define KDIM 9
#define KK 81
#define HH 384
#define WW 384
#define HWSZ (HH*WW)          // 147456
#define WQ 32                 // w columns per block
#define SLICE (WQ*KK)         // 2592 floats = 10368 B
#define NPH (INC*OUTC)        // 9 phases

__device__ __forceinline__ void gll16(const float* g, float* l) {
  __builtin_amdgcn_global_load_lds((const __attribute__((address_space(1))) void*)g,
                                   (__attribute__((address_space(3))) void*)l, 16, 0, 0);
}

__global__ __launch_bounds__(128) void lf_filter_kernel(
    const float* __restrict__ lf, const float* __restrict__ wts,
    const float* __restrict__ bias, float* __restrict__ out)
{
  __shared__ float ldsW[2][SLICE];   // 20736 B -> 7 blocks/CU

  const int t    = threadIdx.x;
  const int wl   = t & 31;          // w within quarter
  const int b    = t >> 5;          // batch
  // XCD-chunked bijective swizzle: 4608 blocks = 8 XCDs x 576
  const int bid  = (int)((blockIdx.x & 7) * 576 + (blockIdx.x >> 3));
  const int wq   = bid & 3;
  const int h    = (bid >> 2) & 127;
  const int s    = bid >> 9;
  const int w    = wq*WQ + wl;
  const int xbase = 3*w - 3;
  const int ybase = 3*h - 3;

  const float* lfb = lf + (size_t)(b*ST + s)*INC*HWSZ;

  // clamped x offsets + masks (static under unroll -> VGPRs)
  int   xi[KDIM];
  float xm[KDIM];
  #pragma unroll
  for (int kx = 0; kx < KDIM; ++kx) {
    const int x = xbase + kx;
    xi[kx] = x < 0 ? 0 : (x > WW-1 ? WW-1 : x);
    xm[kx] = ((unsigned)x < (unsigned)WW) ? 1.f : 0.f;
  }

  const int wu = (t & ~63) * 4;     // wave-uniform LDS dest offset (floats)

  auto stage = [&](int p, int bufsel) {
    const int i = p / OUTC, o = p % OUTC;
    const float* wsrc = wts + ((size_t)(((s*OUTC + o)*INC + i)*OHH + h)*OWW + wq*WQ)*KK;
    float* dst = ldsW[bufsel];
    #pragma unroll
    for (int j = 0; j < 5; ++j)
      gll16(wsrc + (size_t)(j*128 + t)*4, dst + j*512 + wu);
    if (t < 8)
      gll16(wsrc + (size_t)(640 + t)*4, dst + 2560 + wu);
  };

  float acc[OUTC] = {0.f, 0.f, 0.f};

  stage(0, 0);
  __syncthreads();   // prologue drain (exposed once)

  #pragma unroll
  for (int i = 0; i < INC; ++i) {
    // ---- load the 81-tap lf patch into registers, masked once ----
    float lfv[KDIM][KDIM];
    {
      const float* lfr = lfb + (size_t)i*HWSZ;
      #pragma unroll
      for (int ky = 0; ky < KDIM; ++ky) {
        const int y = ybase + ky;          // block-uniform branch
        if ((unsigned)y < (unsigned)HH) {
          const float* rowp = lfr + (size_t)y*WW;
          #pragma unroll
          for (int kx = 0; kx < KDIM; ++kx)
            lfv[ky][kx] = rowp[xi[kx]] * xm[kx];
        } else {
          #pragma unroll
          for (int kx = 0; kx < KDIM; ++kx) lfv[ky][kx] = 0.f;
        }
      }
    }

    #pragma unroll
    for (int o = 0; o < OUTC; ++o) {
      const int p = i*OUTC + o;
      if (p + 1 < NPH) stage(p + 1, (p + 1) & 1);   // in flight during compute

      // ---- compute phase p: pure ds_read + fma, 3-way split chains ----
      const float* wrow = &ldsW[p & 1][wl*KK];
      float a0 = 0.f, a1 = 0.f, a2 = 0.f;
      #pragma unroll
      for (int ky = 0; ky < KDIM; ++ky) {
        #pragma unroll
        for (int kx = 0; kx < KDIM; ++kx) {
          const float wv = wrow[ky*KDIM + kx];   // lane stride 81: conflict-free
          if (kx % 3 == 0)      a0 = fmaf(lfv[ky][kx], wv, a0);
          else if (kx % 3 == 1) a1 = fmaf(lfv[ky][kx], wv, a1);
          else                  a2 = fmaf(lfv[ky][kx], wv, a2);
        }
      }
      acc[o] += (a0 + a1) + a2;

      if (p + 1 < NPH) __syncthreads();   // drains vmcnt: next buf landed; cur free
    }
  }

  // ---- epilogue: bias + clip + coalesced stores ----
  #pragma unroll
  for (int o = 0; o < OUTC; ++o) {
    const float bv = bias[((s*OUTC + o)*OHH + h)*OWW + w];
    float r = acc[o] + bv;
    r = r < 0.f ? 0.f : (r > 1.f ? 1.f : r);
    out[(((size_t)(b*ST + s)*OUTC + o)*OHH + h)*OWW + w] = r;
  }
}

extern "C" void kernel_launch(void* const* d_in, const int* in_sizes, int n_in,
                              void* d_out, int out_size, void* d_ws, size_t ws_size,
                              hipStream_t stream) {
  const float* lf   = (const float*)d_in[0];
  const float* wts  = (const float*)d_in[1];
  const float* bias = (const float*)d_in[2];
  float* out = (float*)d_out;
  dim3 grid(ST * OHH * 4);   // 4608 blocks: (s, h, w-quarter), XCD-swizzled
  dim3 block(128);           // (w:32) x (batch:4)
  hipLaunchKernelGGL(lf_filter_kernel, grid, block, 0, stream, lf, wts, bias, out);
}